// Round 1
// 970.054 us; speedup vs baseline: 1.0609x; 1.0609x over previous
//
#include <hip/hip_runtime.h>

#define N_NODES 200000
#define N_SUPER 20000
#define N_EDGES 640000
#define EMB 256

typedef unsigned short ushort_t;
typedef __attribute__((ext_vector_type(8))) short bf16x8;   // 8 bf16 (4 VGPRs)
typedef __attribute__((ext_vector_type(4))) float f32x4;    // MFMA accumulator

static __device__ __forceinline__ ushort_t f2bf(float f) {
    unsigned int b = __float_as_uint(f);
    unsigned int r = (b + 0x7FFFu + ((b >> 16) & 1u)) >> 16;  // RNE
    return (ushort_t)r;
}

// ---------------------------------------------------------------------------
// out = x
// ---------------------------------------------------------------------------
__global__ __launch_bounds__(256) void copy_f4(const float4* __restrict__ s,
                                               float4* __restrict__ d, int n) {
    int i = blockIdx.x * 256 + threadIdx.x;
    if (i < n) d[i] = s[i];
}

// ---------------------------------------------------------------------------
// CSR build: histogram -> scan (3 kernels) -> bucket fill
// ---------------------------------------------------------------------------
__global__ __launch_bounds__(256) void hist_dst(const int* __restrict__ ei,
                                                int* __restrict__ counts) {
    int e = blockIdx.x * 256 + threadIdx.x;
    if (e < N_EDGES) atomicAdd(&counts[ei[e]], 1);
}

__global__ __launch_bounds__(256) void block_sums(const int* __restrict__ counts,
                                                  int* __restrict__ partials, int N) {
    __shared__ int sh[256];
    int tid = threadIdx.x;
    int i = blockIdx.x * 256 + tid;
    sh[tid] = (i < N) ? counts[i] : 0;
    __syncthreads();
    for (int off = 128; off > 0; off >>= 1) {
        if (tid < off) sh[tid] += sh[tid + off];
        __syncthreads();
    }
    if (tid == 0) partials[blockIdx.x] = sh[0];
}

__global__ __launch_bounds__(256) void scan_partials(int* __restrict__ partials, int NB) {
    __shared__ int sh[256];
    int tid = threadIdx.x;
    int carry = 0;
    for (int c0 = 0; c0 < NB; c0 += 256) {
        int i = c0 + tid;
        int v = (i < NB) ? partials[i] : 0;
        sh[tid] = v;
        __syncthreads();
        for (int off = 1; off < 256; off <<= 1) {
            int t = (tid >= off) ? sh[tid - off] : 0;
            __syncthreads();
            sh[tid] += t;
            __syncthreads();
        }
        int incl = sh[tid];
        int total = sh[255];
        if (i < NB) partials[i] = carry + incl - v;  // exclusive
        carry += total;
        __syncthreads();
    }
}

__global__ __launch_bounds__(256) void scan_blocks(const int* __restrict__ counts,
                                                   const int* __restrict__ partials,
                                                   int* __restrict__ base, int N) {
    __shared__ int sh[256];
    int tid = threadIdx.x;
    int b = blockIdx.x;
    int i = b * 256 + tid;
    int c = (i < N) ? counts[i] : 0;
    sh[tid] = c;
    __syncthreads();
    for (int off = 1; off < 256; off <<= 1) {
        int t = (tid >= off) ? sh[tid - off] : 0;
        __syncthreads();
        sh[tid] += t;
        __syncthreads();
    }
    if (i < N) base[i] = partials[b] + sh[tid] - c;
    if (i == N - 1) base[N] = partials[b] + sh[tid];  // == N_EDGES
}

__global__ __launch_bounds__(256) void fill_bucket(const int* __restrict__ ei,
                                                   const int* __restrict__ base,
                                                   int* __restrict__ cursor,
                                                   int* __restrict__ bucket) {
    int e = blockIdx.x * 256 + threadIdx.x;
    if (e >= N_EDGES) return;
    int d = ei[e];             // dst = row 0
    int s = ei[N_EDGES + e];   // src = row 1
    int pos = atomicAdd(&cursor[d], 1);
    bucket[base[d] + pos] = s;
}

// ---------------------------------------------------------------------------
// Gather-sum: one wave per dst node, sum x1[src] rows, write agg row (bf16)
// exactly once. No fp32 atomics anywhere.
// ---------------------------------------------------------------------------
__global__ __launch_bounds__(256) void gather_sum(const int* __restrict__ bucket,
                                                  const int* __restrict__ base,
                                                  const float* __restrict__ x1,
                                                  ushort_t* __restrict__ agg) {
    int node = blockIdx.x * 4 + (threadIdx.x >> 6);
    int lane = threadIdx.x & 63;
    if (node >= N_NODES) return;
    int j0 = base[node], j1 = base[node + 1];
    float4 acc = make_float4(0.f, 0.f, 0.f, 0.f);
    for (int j = j0; j < j1; ++j) {
        int s = bucket[j];  // wave-uniform -> broadcast load
        float4 v = *(const float4*)(x1 + (size_t)s * EMB + lane * 4);
        acc.x += v.x; acc.y += v.y; acc.z += v.z; acc.w += v.w;
    }
    ushort4 p;
    p.x = f2bf(acc.x); p.y = f2bf(acc.y); p.z = f2bf(acc.z); p.w = f2bf(acc.w);
    *(ushort4*)(agg + (size_t)node * EMB + lane * 4) = p;
}

// ---------------------------------------------------------------------------
// MFMA GEMM with fused scatter/bias epilogue.
//   out[row(m)][c] += sum_k A[m][k]*W[c][k] + bias[c]*coef(m)
//   row(m) = idx ? idx[m] : m ; coef(m) = deg ? (float)deg[m] : 1.0f
//
// Numerics: W is split into hi+lo bf16 (captures ~16 mantissa bits).
//   A_BF16 path (gemm2): A is exact bf16 -> acc += A*Wh + A*Wl  (== today's
//     fp32-weight product to ~2^-16 rel; error unchanged vs passing baseline).
//   fp32 path  (gemm1): A -> hi/lo bf16 -> acc += Ah*Wh + Al*Wh + Ah*Wl
//     (drops only Al*Wl ~ 2^-18 rel).
//
// Structure: 512 threads = 8 waves; wave w owns output cols [32w, 32w+32).
//   Whole B panel (2 n-tiles x 8 k-steps x hi/lo = 32 frags = 128 VGPRs) lives
//   in registers; W (128 KB) is L2-resident so per-block reload is cheap.
//   No LDS, no __syncthreads, no bank conflicts. Blocks grid-stride over
//   16-row tiles (M % 16 == 0 for both calls, no tail).
// MFMA A layout: lane l -> row (l&15), k = (l>>4)*8 + j  (16B contiguous load)
// MFMA C/D layout (m89-verified): col = lane&15, row = (lane>>4)*4 + reg
// ---------------------------------------------------------------------------
template <bool A_BF16>
__global__ __launch_bounds__(512) void gemm_mfma(
    const void* __restrict__ Ap, const float* __restrict__ W,
    const float* __restrict__ bias, const int* __restrict__ deg,
    const int* __restrict__ idx, float* __restrict__ out,
    int M, int ntiles) {
    const int lane = threadIdx.x & 63;
    const int wave = threadIdx.x >> 6;       // 0..7
    const int col0 = wave * 32;
    const int lcol = lane & 15;              // fragment 16-dim index
    const int lk8  = (lane >> 4) * 8;        // fragment k sub-offset

    // ---- B panel: W[col0 + nt*16 + lcol][kk*32 + lk8 + 0..7] as hi/lo bf16 ----
    bf16x8 bh[2][8], bl[2][8];
    #pragma unroll
    for (int nt = 0; nt < 2; ++nt) {
        const float* wr = W + (size_t)(col0 + nt * 16 + lcol) * EMB + lk8;
        #pragma unroll
        for (int kk = 0; kk < 8; ++kk) {
            float4 u0 = *(const float4*)(wr + kk * 32);
            float4 u1 = *(const float4*)(wr + kk * 32 + 4);
            float uv[8] = {u0.x, u0.y, u0.z, u0.w, u1.x, u1.y, u1.z, u1.w};
            bf16x8 h, l;
            #pragma unroll
            for (int j = 0; j < 8; ++j) {
                ushort_t hb = f2bf(uv[j]);
                h[j] = (short)hb;
                float hf = __uint_as_float((unsigned int)hb << 16);
                l[j] = (short)f2bf(uv[j] - hf);
            }
            bh[nt][kk] = h;
            bl[nt][kk] = l;
        }
    }
    float bias_v[2];
    #pragma unroll
    for (int nt = 0; nt < 2; ++nt) bias_v[nt] = bias[col0 + nt * 16 + lcol];

    for (int tile = blockIdx.x; tile < ntiles; tile += gridDim.x) {
        const int row0 = tile * 16;
        f32x4 acc[2] = {{0.f, 0.f, 0.f, 0.f}, {0.f, 0.f, 0.f, 0.f}};

        if constexpr (A_BF16) {
            const ushort_t* A0 = (const ushort_t*)Ap + (size_t)(row0 + lcol) * EMB + lk8;
            #pragma unroll
            for (int kk = 0; kk < 8; ++kk) {
                bf16x8 a = *(const bf16x8*)(A0 + kk * 32);
                #pragma unroll
                for (int nt = 0; nt < 2; ++nt) {
                    acc[nt] = __builtin_amdgcn_mfma_f32_16x16x32_bf16(a, bh[nt][kk], acc[nt], 0, 0, 0);
                    acc[nt] = __builtin_amdgcn_mfma_f32_16x16x32_bf16(a, bl[nt][kk], acc[nt], 0, 0, 0);
                }
            }
        } else {
            const float* A0 = (const float*)Ap + (size_t)(row0 + lcol) * EMB + lk8;
            #pragma unroll
            for (int kk = 0; kk < 8; ++kk) {
                float4 a0 = *(const float4*)(A0 + kk * 32);
                float4 a1 = *(const float4*)(A0 + kk * 32 + 4);
                float av[8] = {a0.x, a0.y, a0.z, a0.w, a1.x, a1.y, a1.z, a1.w};
                bf16x8 ah, al;
                #pragma unroll
                for (int j = 0; j < 8; ++j) {
                    ushort_t hb = f2bf(av[j]);
                    ah[j] = (short)hb;
                    float hf = __uint_as_float((unsigned int)hb << 16);
                    al[j] = (short)f2bf(av[j] - hf);
                }
                #pragma unroll
                for (int nt = 0; nt < 2; ++nt) {
                    acc[nt] = __builtin_amdgcn_mfma_f32_16x16x32_bf16(ah, bh[nt][kk], acc[nt], 0, 0, 0);
                    acc[nt] = __builtin_amdgcn_mfma_f32_16x16x32_bf16(al, bh[nt][kk], acc[nt], 0, 0, 0);
                    acc[nt] = __builtin_amdgcn_mfma_f32_16x16x32_bf16(ah, bl[nt][kk], acc[nt], 0, 0, 0);
                }
            }
        }

        // epilogue: out[orow][col0 + nt*16 + lcol] += acc[nt][j] + bias*coef
        #pragma unroll
        for (int j = 0; j < 4; ++j) {
            const int r = row0 + (lane >> 4) * 4 + j;
            const int orow = idx ? idx[r] : r;
            const float coef = deg ? (float)deg[r] : 1.0f;
            float* op = out + (size_t)orow * EMB + col0 + lcol;
            #pragma unroll
            for (int nt = 0; nt < 2; ++nt)
                op[nt * 16] += acc[nt][j] + bias_v[nt] * coef;
        }
    }
}

extern "C" void kernel_launch(void* const* d_in, const int* in_sizes, int n_in,
                              void* d_out, int out_size, void* d_ws, size_t ws_size,
                              hipStream_t stream) {
    const float* x    = (const float*)d_in[0];
    const float* snx  = (const float*)d_in[1];
    const int*   ei   = (const int*)d_in[2];    // [2, E] flat: row0=dst, row1=src
    const int*   sidx = (const int*)d_in[3];    // [S]
    const float* W1   = (const float*)d_in[5];
    const float* b1   = (const float*)d_in[6];
    const float* W2   = (const float*)d_in[7];
    const float* b2   = (const float*)d_in[8];
    float* out = (float*)d_out;

    // ws layout (total ~107.4 MB, unchanged):
    ushort_t* agg  = (ushort_t*)d_ws;                       // [N_NODES*EMB] bf16
    int* counts    = (int*)(agg + (size_t)N_NODES * EMB);   // [N_NODES] (= deg)
    int* cursor    = counts + N_NODES;                      // [N_NODES]
    int* base      = cursor + N_NODES;                      // [N_NODES+1]
    int* bucket    = base + (N_NODES + 1);                  // [N_EDGES]
    int* partials  = bucket + N_EDGES;                      // [1024]

    const int NB = (N_NODES + 255) / 256;  // 782

    // zero counts + cursor (adjacent, 1.6 MB)
    hipMemsetAsync(counts, 0, 2 * N_NODES * sizeof(int), stream);

    // out = x
    int n4 = N_NODES * EMB / 4;
    copy_f4<<<(n4 + 255) / 256, 256, 0, stream>>>((const float4*)x, (float4*)out, n4);

    // out[sidx] += snx @ W1^T + b1   (-> out now holds x1)
    gemm_mfma<false><<<512, 512, 0, stream>>>(snx, W1, b1, nullptr, sidx, out,
                                              N_SUPER, N_SUPER / 16);

    // CSR build by dst
    hist_dst<<<(N_EDGES + 255) / 256, 256, 0, stream>>>(ei, counts);
    block_sums<<<NB, 256, 0, stream>>>(counts, partials, N_NODES);
    scan_partials<<<1, 256, 0, stream>>>(partials, NB);
    scan_blocks<<<NB, 256, 0, stream>>>(counts, partials, base, N_NODES);
    fill_bucket<<<(N_EDGES + 255) / 256, 256, 0, stream>>>(ei, base, cursor, bucket);

    // agg[n] = sum_{e: dst=n} x1[src_e]   (bf16 rows, written once)
    gather_sum<<<(N_NODES + 3) / 4, 256, 0, stream>>>(bucket, base, out, agg);

    // out += agg @ W2^T + deg * b2
    gemm_mfma<true><<<1024, 512, 0, stream>>>(agg, W2, b2, counts, nullptr, out,
                                              N_NODES, N_NODES / 16);
}

// Round 2
// 881.137 us; speedup vs baseline: 1.1679x; 1.1009x over previous
//
#include <hip/hip_runtime.h>

#define N_NODES 200000
#define N_SUPER 20000
#define N_EDGES 640000
#define EMB 256

typedef unsigned short ushort_t;
typedef __attribute__((ext_vector_type(8))) short bf16x8;   // 8 bf16 (4 VGPRs)
typedef __attribute__((ext_vector_type(4))) float f32x4;    // MFMA accumulator

static __device__ __forceinline__ ushort_t f2bf(float f) {
    unsigned int b = __float_as_uint(f);
    unsigned int r = (b + 0x7FFFu + ((b >> 16) & 1u)) >> 16;  // RNE
    return (ushort_t)r;
}

// ---------------------------------------------------------------------------
// out = x
// ---------------------------------------------------------------------------
__global__ __launch_bounds__(256) void copy_f4(const float4* __restrict__ s,
                                               float4* __restrict__ d, int n) {
    int i = blockIdx.x * 256 + threadIdx.x;
    if (i < n) d[i] = s[i];
}

// ---------------------------------------------------------------------------
// CSR build: histogram -> scan (3 kernels) -> bucket fill
// ---------------------------------------------------------------------------
__global__ __launch_bounds__(256) void hist_dst(const int* __restrict__ ei,
                                                int* __restrict__ counts) {
    int e = blockIdx.x * 256 + threadIdx.x;
    if (e < N_EDGES) atomicAdd(&counts[ei[e]], 1);
}

__global__ __launch_bounds__(256) void block_sums(const int* __restrict__ counts,
                                                  int* __restrict__ partials, int N) {
    __shared__ int sh[256];
    int tid = threadIdx.x;
    int i = blockIdx.x * 256 + tid;
    sh[tid] = (i < N) ? counts[i] : 0;
    __syncthreads();
    for (int off = 128; off > 0; off >>= 1) {
        if (tid < off) sh[tid] += sh[tid + off];
        __syncthreads();
    }
    if (tid == 0) partials[blockIdx.x] = sh[0];
}

__global__ __launch_bounds__(256) void scan_partials(int* __restrict__ partials, int NB) {
    __shared__ int sh[256];
    int tid = threadIdx.x;
    int carry = 0;
    for (int c0 = 0; c0 < NB; c0 += 256) {
        int i = c0 + tid;
        int v = (i < NB) ? partials[i] : 0;
        sh[tid] = v;
        __syncthreads();
        for (int off = 1; off < 256; off <<= 1) {
            int t = (tid >= off) ? sh[tid - off] : 0;
            __syncthreads();
            sh[tid] += t;
            __syncthreads();
        }
        int incl = sh[tid];
        int total = sh[255];
        if (i < NB) partials[i] = carry + incl - v;  // exclusive
        carry += total;
        __syncthreads();
    }
}

__global__ __launch_bounds__(256) void scan_blocks(const int* __restrict__ counts,
                                                   const int* __restrict__ partials,
                                                   int* __restrict__ base, int N) {
    __shared__ int sh[256];
    int tid = threadIdx.x;
    int b = blockIdx.x;
    int i = b * 256 + tid;
    int c = (i < N) ? counts[i] : 0;
    sh[tid] = c;
    __syncthreads();
    for (int off = 1; off < 256; off <<= 1) {
        int t = (tid >= off) ? sh[tid - off] : 0;
        __syncthreads();
        sh[tid] += t;
        __syncthreads();
    }
    if (i < N) base[i] = partials[b] + sh[tid] - c;
    if (i == N - 1) base[N] = partials[b] + sh[tid];  // == N_EDGES
}

__global__ __launch_bounds__(256) void fill_bucket(const int* __restrict__ ei,
                                                   const int* __restrict__ base,
                                                   int* __restrict__ cursor,
                                                   int* __restrict__ bucket) {
    int e = blockIdx.x * 256 + threadIdx.x;
    if (e >= N_EDGES) return;
    int d = ei[e];             // dst = row 0
    int s = ei[N_EDGES + e];   // src = row 1
    int pos = atomicAdd(&cursor[d], 1);
    bucket[base[d] + pos] = s;
}

// ---------------------------------------------------------------------------
// Gather-sum: one wave per dst node, sum x1[src] rows, write agg row (bf16)
// exactly once. 2-deep software pipeline on the row loads.
// ---------------------------------------------------------------------------
__global__ __launch_bounds__(256) void gather_sum(const int* __restrict__ bucket,
                                                  const int* __restrict__ base,
                                                  const float* __restrict__ x1,
                                                  ushort_t* __restrict__ agg) {
    int node = blockIdx.x * 4 + (threadIdx.x >> 6);
    int lane = threadIdx.x & 63;
    if (node >= N_NODES) return;
    int j0 = base[node], j1 = base[node + 1];
    float4 acc = make_float4(0.f, 0.f, 0.f, 0.f);
    int j = j0;
    for (; j + 1 < j1; j += 2) {
        int s0 = bucket[j];      // wave-uniform -> broadcast loads
        int s1 = bucket[j + 1];
        float4 v0 = *(const float4*)(x1 + (size_t)s0 * EMB + lane * 4);
        float4 v1 = *(const float4*)(x1 + (size_t)s1 * EMB + lane * 4);
        acc.x += v0.x + v1.x; acc.y += v0.y + v1.y;
        acc.z += v0.z + v1.z; acc.w += v0.w + v1.w;
    }
    if (j < j1) {
        int s0 = bucket[j];
        float4 v0 = *(const float4*)(x1 + (size_t)s0 * EMB + lane * 4);
        acc.x += v0.x; acc.y += v0.y; acc.z += v0.z; acc.w += v0.w;
    }
    ushort4 p;
    p.x = f2bf(acc.x); p.y = f2bf(acc.y); p.z = f2bf(acc.z); p.w = f2bf(acc.w);
    *(ushort4*)(agg + (size_t)node * EMB + lane * 4) = p;
}

// ---------------------------------------------------------------------------
// MFMA GEMM with fused scatter/bias epilogue.
//   out[row(m)][c] += sum_k A[m][k]*W[c][k] + bias[c]*coef(m)
//   row(m) = idx ? idx[m] : m ; coef(m) = deg ? (float)deg[m] : 1.0f
//
// Numerics identical to previous passing version (absmax 0.0625):
//   W split hi+lo bf16; A exact bf16 (gemm2) or hi/lo bf16 split (gemm1).
//
// Key latency fix (r1): the 8 out-row RMWs were serialized (runtime idx ->
// compiler can't prove no-alias -> load/store/load/store chain of ~900-cyc
// HBM round trips = ~7K cyc/tile). Now: prefetch ALL out values + idx/deg
// BEFORE the k-loop (overlaps with A loads + MFMAs), store all at the end.
// Rows are provably distinct at runtime (unique idx), so this is exact.
// ---------------------------------------------------------------------------
template <bool A_BF16>
__global__ __launch_bounds__(512) void gemm_mfma(
    const void* __restrict__ Ap, const float* __restrict__ W,
    const float* __restrict__ bias, const int* __restrict__ deg,
    const int* __restrict__ idx, float* __restrict__ out,
    int M, int ntiles) {
    const int lane = threadIdx.x & 63;
    const int wave = threadIdx.x >> 6;       // 0..7
    const int col0 = wave * 32;
    const int lcol = lane & 15;              // fragment 16-dim index
    const int lk8  = (lane >> 4) * 8;        // fragment k sub-offset

    // ---- B panel: W[col0 + nt*16 + lcol][kk*32 + lk8 + 0..7] as hi/lo bf16 ----
    bf16x8 bh[2][8], bl[2][8];
    #pragma unroll
    for (int nt = 0; nt < 2; ++nt) {
        const float* wr = W + (size_t)(col0 + nt * 16 + lcol) * EMB + lk8;
        #pragma unroll
        for (int kk = 0; kk < 8; ++kk) {
            float4 u0 = *(const float4*)(wr + kk * 32);
            float4 u1 = *(const float4*)(wr + kk * 32 + 4);
            float uv[8] = {u0.x, u0.y, u0.z, u0.w, u1.x, u1.y, u1.z, u1.w};
            bf16x8 h, l;
            #pragma unroll
            for (int j = 0; j < 8; ++j) {
                ushort_t hb = f2bf(uv[j]);
                h[j] = (short)hb;
                float hf = __uint_as_float((unsigned int)hb << 16);
                l[j] = (short)f2bf(uv[j] - hf);
            }
            bh[nt][kk] = h;
            bl[nt][kk] = l;
        }
    }
    float bias_v[2];
    #pragma unroll
    for (int nt = 0; nt < 2; ++nt) bias_v[nt] = bias[col0 + nt * 16 + lcol];

    for (int tile = blockIdx.x; tile < ntiles; tile += gridDim.x) {
        const int row0 = tile * 16;

        // ---- prefetch epilogue state: idx/deg + current out values ----
        // (all 8 loads issued up front; latency hides under A loads + MFMAs)
        int   orow[4];
        float coef[4];
        float oldv[4][2];
        #pragma unroll
        for (int j = 0; j < 4; ++j) {
            const int r = row0 + (lane >> 4) * 4 + j;
            orow[j] = idx ? idx[r] : r;
            coef[j] = deg ? (float)deg[r] : 1.0f;
            const float* op = out + (size_t)orow[j] * EMB + col0 + lcol;
            oldv[j][0] = op[0];
            oldv[j][1] = op[16];
        }

        f32x4 acc[2] = {{0.f, 0.f, 0.f, 0.f}, {0.f, 0.f, 0.f, 0.f}};

        if constexpr (A_BF16) {
            const ushort_t* A0 = (const ushort_t*)Ap + (size_t)(row0 + lcol) * EMB + lk8;
            #pragma unroll
            for (int kk = 0; kk < 8; ++kk) {
                bf16x8 a = *(const bf16x8*)(A0 + kk * 32);
                #pragma unroll
                for (int nt = 0; nt < 2; ++nt) {
                    acc[nt] = __builtin_amdgcn_mfma_f32_16x16x32_bf16(a, bh[nt][kk], acc[nt], 0, 0, 0);
                    acc[nt] = __builtin_amdgcn_mfma_f32_16x16x32_bf16(a, bl[nt][kk], acc[nt], 0, 0, 0);
                }
            }
        } else {
            const float* A0 = (const float*)Ap + (size_t)(row0 + lcol) * EMB + lk8;
            #pragma unroll
            for (int kk = 0; kk < 8; ++kk) {
                float4 a0 = *(const float4*)(A0 + kk * 32);
                float4 a1 = *(const float4*)(A0 + kk * 32 + 4);
                float av[8] = {a0.x, a0.y, a0.z, a0.w, a1.x, a1.y, a1.z, a1.w};
                bf16x8 ah, al;
                #pragma unroll
                for (int j = 0; j < 8; ++j) {
                    ushort_t hb = f2bf(av[j]);
                    ah[j] = (short)hb;
                    float hf = __uint_as_float((unsigned int)hb << 16);
                    al[j] = (short)f2bf(av[j] - hf);
                }
                #pragma unroll
                for (int nt = 0; nt < 2; ++nt) {
                    acc[nt] = __builtin_amdgcn_mfma_f32_16x16x32_bf16(ah, bh[nt][kk], acc[nt], 0, 0, 0);
                    acc[nt] = __builtin_amdgcn_mfma_f32_16x16x32_bf16(al, bh[nt][kk], acc[nt], 0, 0, 0);
                    acc[nt] = __builtin_amdgcn_mfma_f32_16x16x32_bf16(ah, bl[nt][kk], acc[nt], 0, 0, 0);
                }
            }
        }

        // ---- store phase: all values already in registers ----
        #pragma unroll
        for (int j = 0; j < 4; ++j) {
            float* op = out + (size_t)orow[j] * EMB + col0 + lcol;
            op[0]  = oldv[j][0] + acc[0][j] + bias_v[0] * coef[j];
            op[16] = oldv[j][1] + acc[1][j] + bias_v[1] * coef[j];
        }
    }
}

extern "C" void kernel_launch(void* const* d_in, const int* in_sizes, int n_in,
                              void* d_out, int out_size, void* d_ws, size_t ws_size,
                              hipStream_t stream) {
    const float* x    = (const float*)d_in[0];
    const float* snx  = (const float*)d_in[1];
    const int*   ei   = (const int*)d_in[2];    // [2, E] flat: row0=dst, row1=src
    const int*   sidx = (const int*)d_in[3];    // [S]
    const float* W1   = (const float*)d_in[5];
    const float* b1   = (const float*)d_in[6];
    const float* W2   = (const float*)d_in[7];
    const float* b2   = (const float*)d_in[8];
    float* out = (float*)d_out;

    // ws layout (total ~107.4 MB, unchanged):
    ushort_t* agg  = (ushort_t*)d_ws;                       // [N_NODES*EMB] bf16
    int* counts    = (int*)(agg + (size_t)N_NODES * EMB);   // [N_NODES] (= deg)
    int* cursor    = counts + N_NODES;                      // [N_NODES]
    int* base      = cursor + N_NODES;                      // [N_NODES+1]
    int* bucket    = base + (N_NODES + 1);                  // [N_EDGES]
    int* partials  = bucket + N_EDGES;                      // [1024]

    const int NB = (N_NODES + 255) / 256;  // 782

    // zero counts + cursor (adjacent, 1.6 MB)
    hipMemsetAsync(counts, 0, 2 * N_NODES * sizeof(int), stream);

    // out = x
    int n4 = N_NODES * EMB / 4;
    copy_f4<<<(n4 + 255) / 256, 256, 0, stream>>>((const float4*)x, (float4*)out, n4);

    // out[sidx] += snx @ W1^T + b1   (-> out now holds x1)
    gemm_mfma<false><<<512, 512, 0, stream>>>(snx, W1, b1, nullptr, sidx, out,
                                              N_SUPER, N_SUPER / 16);

    // CSR build by dst
    hist_dst<<<(N_EDGES + 255) / 256, 256, 0, stream>>>(ei, counts);
    block_sums<<<NB, 256, 0, stream>>>(counts, partials, N_NODES);
    scan_partials<<<1, 256, 0, stream>>>(partials, NB);
    scan_blocks<<<NB, 256, 0, stream>>>(counts, partials, base, N_NODES);
    fill_bucket<<<(N_EDGES + 255) / 256, 256, 0, stream>>>(ei, base, cursor, bucket);

    // agg[n] = sum_{e: dst=n} x1[src_e]   (bf16 rows, written once)
    gather_sum<<<(N_NODES + 3) / 4, 256, 0, stream>>>(bucket, base, out, agg);

    // out += agg @ W2^T + deg * b2
    gemm_mfma<true><<<1024, 512, 0, stream>>>(agg, W2, b2, counts, nullptr, out,
                                              N_NODES, N_NODES / 16);
}